// Round 1
// baseline (219.723 us; speedup 1.0000x reference)
//
#include <hip/hip_runtime.h>
#include <stdint.h>
#include <stddef.h>

// CliffordLinear as one bf16 GEMM:
//   out[b, o*8+l] = sum_{i,k} X[b, i*8+k] * Wt[o*8+l, i*8+k] + bias[o*8+l]
//   Wt[(o,l),(i,k)] = sum_j cayley[j,k,l] * W[o,i,j]
// M=8192, N=2048, K=2048. bf16 inputs, fp32 MFMA accumulate.

typedef __bf16 bf16x8 __attribute__((ext_vector_type(8)));
typedef float  f32x4  __attribute__((ext_vector_type(4)));

#define BM 128
#define BN 128
#define BK 32

__device__ __forceinline__ void async_copy16(void* lds_dst, const void* g_src) {
    // global -> LDS direct copy, 16B per lane; LDS dest must be wave-uniform base,
    // HW scatters lane i to base + i*16.
    __builtin_amdgcn_global_load_lds(
        (__attribute__((address_space(1))) void*)g_src,
        (__attribute__((address_space(3))) void*)lds_dst,
        16, 0, 0);
}

// ---------------- kernel 1: fp32 -> bf16 cast of X ----------------
__global__ __launch_bounds__(256) void cast_bf16_kernel(
    const float* __restrict__ in, __bf16* __restrict__ out, long n)
{
    long i = ((long)blockIdx.x * 256 + threadIdx.x) * 8;
    if (i + 7 >= n + 8) return;   // grid sized exactly; keep a cheap guard
    if (i + 8 <= n) {
        const f32x4* p = (const f32x4*)(in + i);
        f32x4 v0 = p[0];
        f32x4 v1 = p[1];
        bf16x8 o;
        o[0] = (__bf16)v0[0]; o[1] = (__bf16)v0[1];
        o[2] = (__bf16)v0[2]; o[3] = (__bf16)v0[3];
        o[4] = (__bf16)v1[0]; o[5] = (__bf16)v1[1];
        o[6] = (__bf16)v1[2]; o[7] = (__bf16)v1[3];
        *(bf16x8*)(out + i) = o;
    }
}

// ---------------- kernel 2: fold Cayley into weight ----------------
// Wt[n][kk] (bf16, [N][K]) with n=o*8+l, kk=i*8+k:
//   Wt = sum_j cayley[j*64 + k*8 + l] * W[o*Cin*8 + i*8 + j]
__global__ __launch_bounds__(256) void build_wt_kernel(
    const float* __restrict__ W,
    const float* __restrict__ cayley,
    __bf16* __restrict__ Wt,
    int Cin, int Cout)
{
    __shared__ float Cay[512];
    for (int t = threadIdx.x; t < 512; t += 256) Cay[t] = cayley[t];
    __syncthreads();

    int flat = blockIdx.x * 256 + threadIdx.x;   // flat = n*Cin + i
    int total = Cout * 8 * Cin;
    if (flat >= total) return;
    int i = flat % Cin;
    int n = flat / Cin;
    int o = n >> 3, l = n & 7;

    const float* wrow = W + ((size_t)o * Cin + i) * 8;
    float w8[8];
    #pragma unroll
    for (int j = 0; j < 8; ++j) w8[j] = wrow[j];

    bf16x8 outv;
    #pragma unroll
    for (int k = 0; k < 8; ++k) {
        float s = 0.f;
        #pragma unroll
        for (int j = 0; j < 8; ++j) s += Cay[j * 64 + k * 8 + l] * w8[j];
        outv[k] = (__bf16)s;
    }
    *(bf16x8*)(Wt + (size_t)n * (Cin * 8) + i * 8) = outv;
}

// ---------------- kernel 3: bf16 GEMM, C = A * Bt^T + bias ----------------
// A  : [M][K] bf16 (row-major)
// Bt : [N][K] bf16 (row-major, i.e. B transposed)
// C  : [M][N] fp32
// m97-lineage structure: 128x128 tile, BK=32, 4 waves, 4x4 16x16x32 MFMA/wave,
// global_load_lds width-16 staging, 2-barrier K-loop.
__global__ __launch_bounds__(256) void gemm_bt_kernel(
    const __bf16* __restrict__ A,
    const __bf16* __restrict__ Bt,
    const float*  __restrict__ bias,
    float* __restrict__ C,
    int M, int N, int K)
{
    __shared__ __align__(16) __bf16 As[BM * BK];  // 8 KB, row-major [128][32]
    __shared__ __align__(16) __bf16 Bs[BN * BK];  // 8 KB, row-major [128][32]

    const int tid  = threadIdx.x;
    const int wave = tid >> 6;
    const int lane = tid & 63;
    const int quad = lane >> 4;   // 0..3
    const int l16  = lane & 15;   // 0..15

    const int mBase = blockIdx.y * BM;
    const int nBase = blockIdx.x * BN;

    // --- staging assignment: wave w loads chunks {2w, 2w+1} of A and of B.
    // chunk c = rows [c*16, c*16+16) of the tile; one wave-issue = 1 KB LDS.
    const int rowInChunk = lane >> 2;        // 0..15
    const int kPart      = (lane & 3) * 8;   // element offset within BK row

    const int c0 = wave * 2;
    const int c1 = wave * 2 + 1;

    const __bf16* gA0 = A  + (size_t)(mBase + c0 * 16 + rowInChunk) * K + kPart;
    const __bf16* gA1 = A  + (size_t)(mBase + c1 * 16 + rowInChunk) * K + kPart;
    const __bf16* gB0 = Bt + (size_t)(nBase + c0 * 16 + rowInChunk) * K + kPart;
    const __bf16* gB1 = Bt + (size_t)(nBase + c1 * 16 + rowInChunk) * K + kPart;

    __bf16* lA0 = As + c0 * 512;   // 512 bf16 = 1024 B per chunk
    __bf16* lA1 = As + c1 * 512;
    __bf16* lB0 = Bs + c0 * 512;
    __bf16* lB1 = Bs + c1 * 512;

    // --- compute assignment: wave quadrant (64x64), 4x4 grid of 16x16 tiles
    const int wm = (wave >> 1) * 64;
    const int wn = (wave & 1) * 64;

    // A-fragment: A[m=l16][k=quad*8+j]  -> As[(wm + mt*16 + l16)*32 + quad*8]
    const __bf16* fragA = As + (size_t)(wm + l16) * BK + quad * 8;
    const __bf16* fragB = Bs + (size_t)(wn + l16) * BK + quad * 8;

    f32x4 acc[4][4] = {};

    for (int k0 = 0; k0 < K; k0 += BK) {
        __syncthreads();   // previous iteration's LDS reads done
        async_copy16(lA0, gA0 + k0);
        async_copy16(lA1, gA1 + k0);
        async_copy16(lB0, gB0 + k0);
        async_copy16(lB1, gB1 + k0);
        __syncthreads();   // compiler drains vmcnt(0) before s_barrier

        bf16x8 af[4], bfr[4];
        #pragma unroll
        for (int mt = 0; mt < 4; ++mt)
            af[mt] = *(const bf16x8*)(fragA + (size_t)mt * 16 * BK);
        #pragma unroll
        for (int nt = 0; nt < 4; ++nt)
            bfr[nt] = *(const bf16x8*)(fragB + (size_t)nt * 16 * BK);

        #pragma unroll
        for (int mt = 0; mt < 4; ++mt)
            #pragma unroll
            for (int nt = 0; nt < 4; ++nt)
                acc[mt][nt] = __builtin_amdgcn_mfma_f32_16x16x32_bf16(
                    af[mt], bfr[nt], acc[mt][nt], 0, 0, 0);
    }

    // --- epilogue: C/D layout col = lane&15, row = quad*4 + reg
    float bv[4];
    #pragma unroll
    for (int nt = 0; nt < 4; ++nt)
        bv[nt] = bias[nBase + wn + nt * 16 + l16];

    #pragma unroll
    for (int mt = 0; mt < 4; ++mt) {
        #pragma unroll
        for (int nt = 0; nt < 4; ++nt) {
            const int col = nBase + wn + nt * 16 + l16;
            #pragma unroll
            for (int r = 0; r < 4; ++r) {
                const int row = mBase + wm + mt * 16 + quad * 4 + r;
                C[(size_t)row * N + col] = acc[mt][nt][r] + bv[nt];
            }
        }
    }
}

extern "C" void kernel_launch(void* const* d_in, const int* in_sizes, int n_in,
                              void* d_out, int out_size, void* d_ws, size_t ws_size,
                              hipStream_t stream) {
    const float* x      = (const float*)d_in[0];  // [B][Cin][8]
    const float* weight = (const float*)d_in[1];  // [Cout][Cin][8]
    const float* bias   = (const float*)d_in[2];  // [Cout][8]
    const float* cayley = (const float*)d_in[3];  // [8][8][8]
    float* out = (float*)d_out;                   // [B][Cout][8]

    const int Cout = in_sizes[2] / 8;
    const int Cin  = in_sizes[1] / (Cout * 8);
    const int Bm   = in_sizes[0] / (Cin * 8);
    const int M = Bm;          // 8192
    const int N = Cout * 8;    // 2048
    const int K = Cin * 8;     // 2048

    __bf16* Xb = (__bf16*)d_ws;                                    // M*K bf16 = 32 MB
    __bf16* Wt = (__bf16*)((char*)d_ws + (size_t)M * K * 2);       // N*K bf16 = 8 MB

    // 1) cast X to bf16
    long nx = (long)M * K;
    int castBlocks = (int)((nx / 8 + 255) / 256);
    cast_bf16_kernel<<<castBlocks, 256, 0, stream>>>(x, Xb, nx);

    // 2) fold cayley into weight -> Wt [N][K] bf16
    int totalWt = N * Cin;
    build_wt_kernel<<<(totalWt + 255) / 256, 256, 0, stream>>>(weight, cayley, Wt, Cin, Cout);

    // 3) GEMM
    dim3 grid(N / BN, M / BM);   // 16 x 64 = 1024 blocks
    gemm_bt_kernel<<<grid, 256, 0, stream>>>(Xb, Wt, bias, out, M, N, K);
}